// Round 9
// baseline (450.959 us; speedup 1.0000x reference)
//
#include <hip/hip_runtime.h>
#include <hip/hip_cooperative_groups.h>
#include <math.h>

namespace cg = cooperative_groups;

#define NUM_USERS 100000
#define NUM_ITEMS 50000
#define NN 150000               // total nodes
#define EE 1200000              // total directed edges (2 * E_DIR)
#define NB 586                  // ceil(NN/256) scan blocks
#define NNP (NB * 256)          // padded node count = 150016
#define G8_BLOCKS 4688          // ceil(NN*8/256) for 8-lane-per-node kernels

typedef unsigned short ushort_t;
typedef unsigned int uint_t;

__device__ __forceinline__ uint_t pack2(float lo, float hi) {   // 2x fp32 -> bf16x2 RNE
    uint_t a = __float_as_uint(lo);
    uint_t b = __float_as_uint(hi);
    a = (a + 0x7FFFu + ((a >> 16) & 1u)) >> 16;
    b = (b + 0x7FFFu + ((b >> 16) & 1u)) & 0xFFFF0000u;
    return a | b;
}
__device__ __forceinline__ float lo16(uint_t x) { return __uint_as_float(x << 16); }
__device__ __forceinline__ float hi16(uint_t x) { return __uint_as_float(x & 0xFFFF0000u); }

// ---- fused edge MLP + count/rank (ONE atomic per edge, issued EARLY) --------
__global__ void mlp_count_kernel(const float* __restrict__ feats,
                                 const float* __restrict__ w1,
                                 const float* __restrict__ b1,
                                 const float* __restrict__ w2,
                                 const float* __restrict__ b2,
                                 const int* __restrict__ col,
                                 int2* __restrict__ er,
                                 int* __restrict__ counts) {
    __shared__ float sw1[256];
    __shared__ float sb1[32];
    __shared__ float sw2[32];
    __shared__ float sb2;
    int t = threadIdx.x;
    sw1[t] = w1[t];
    if (t < 32) { sb1[t] = b1[t]; sw2[t] = w2[t]; }
    if (t == 0) sb2 = b2[0];
    __syncthreads();
    int e = blockIdx.x * 256 + t;
    if (e >= EE) return;
    int c = col[e];
    int k = atomicAdd(&counts[c], 1);      // issue first: latency hides under MLP
    const float4* fp = (const float4*)(feats + (size_t)e * 8);
    float4 fa = fp[0], fb = fp[1];
    float f[8] = {fa.x, fa.y, fa.z, fa.w, fb.x, fb.y, fb.z, fb.w};
    float s = sb2;
#pragma unroll
    for (int j = 0; j < 32; ++j) {
        float h = sb1[j];
#pragma unroll
        for (int i = 0; i < 8; ++i) h = fmaf(f[i], sw1[i * 32 + j], h);
        h = fmaxf(h, 0.f);
        s = fmaf(h, sw2[j], s);
    }
    float w = 1.f / (1.f + expf(-s));
    er[e] = make_int2(k, __float_as_int(w));
}

// ---- cooperative: scan counts -> offs, then atomic-free CSR fill ------------
__global__ void scan_fill_kernel(const int* __restrict__ counts,
                                 int* __restrict__ offs,
                                 int* __restrict__ partials,
                                 const int2* __restrict__ er,
                                 const int* __restrict__ row,
                                 const int* __restrict__ col,
                                 int2* __restrict__ packed) {
    cg::grid_group grid = cg::this_grid();
    __shared__ int sp[768];                      // NB=586 padded to 768
    __shared__ int wsum[4];
    int t = threadIdx.x;
    int i = blockIdx.x * 256 + t;
    int lane = t & 63;

    // phase 1: per-block exclusive scan of counts; block totals
    {
        int v = counts[i];                       // [NN,NNP) pre-zeroed
        int s = v;
#pragma unroll
        for (int off = 1; off < 64; off <<= 1) {
            int u = __shfl_up(s, off, 64);
            if (lane >= off) s += u;
        }
        if (lane == 63) wsum[t >> 6] = s;
        __syncthreads();
        int add = 0;
        for (int w = 0; w < (t >> 6); ++w) add += wsum[w];
        offs[i] = s - v + add;
        if (t == 255) partials[blockIdx.x] = s + add;
    }
    grid.sync();

    // phase 2: every block scans partials in LDS, adds its own base
    {
#pragma unroll
        for (int k = 0; k < 3; ++k) {
            int idx = t + k * 256;
            sp[idx] = (idx < NB) ? partials[idx] : 0;
        }
        __syncthreads();
        int v0 = sp[3 * t], v1 = sp[3 * t + 1], v2 = sp[3 * t + 2];
        int tot = v0 + v1 + v2;
        int s = tot;
#pragma unroll
        for (int off = 1; off < 64; off <<= 1) {
            int u = __shfl_up(s, off, 64);
            if (lane >= off) s += u;
        }
        __syncthreads();                          // wsum reuse
        if (lane == 63) wsum[t >> 6] = s;
        __syncthreads();
        int add = 0;
        for (int w = 0; w < (t >> 6); ++w) add += wsum[w];
        int excl = s - tot + add;
        sp[3 * t]     = excl;
        sp[3 * t + 1] = excl + v0;
        sp[3 * t + 2] = excl + v0 + v1;
        __syncthreads();
        offs[i] = offs[i] + sp[blockIdx.x];
    }
    grid.sync();

    // phase 3: fill CSR, 8 edges per thread, coalesced reads
    for (int e = i; e < EE; e += NNP) {
        int2 p = er[e];
        int slot = offs[col[e]] + p.x;
        packed[slot] = make_int2(row[e], p.y);
    }
}

// ---- gather core: 8 lanes per node, 16B loads; a0/a1 = cols 8c..8c+7 --------
__device__ __forceinline__ void gather_node8(const ushort_t* __restrict__ zin,
                                             const int2* __restrict__ packed,
                                             int beg, int end, unsigned c,
                                             float4& a0, float4& a1) {
    for (int base = beg; base < end; base += 8) {
        int m = end - base; if (m > 8) m = 8;
        int r = 0; float w = 0.f;
        if ((int)c < m) {
            int2 p = packed[base + (int)c];
            r = p.x; w = __int_as_float(p.y);
        }
        int rj[8]; float wj[8]; uint4 vj[8];
#pragma unroll
        for (int u = 0; u < 8; ++u) {
            int idx = (u < m) ? u : (m - 1);       // clamp: re-read last valid row
            rj[u] = __shfl(r, idx, 8);
            wj[u] = __shfl(w, u, 8);               // lanes >= m carry w=0
        }
#pragma unroll
        for (int u = 0; u < 8; ++u)
            vj[u] = *(const uint4*)(zin + (size_t)(uint_t)rj[u] * 64u + c * 8u);
#pragma unroll
        for (int u = 0; u < 8; ++u) {
            float ww = wj[u]; uint4 v = vj[u];
            a0.x = fmaf(ww, lo16(v.x), a0.x);
            a0.y = fmaf(ww, hi16(v.x), a0.y);
            a0.z = fmaf(ww, lo16(v.y), a0.z);
            a0.w = fmaf(ww, hi16(v.y), a0.w);
            a1.x = fmaf(ww, lo16(v.z), a1.x);
            a1.y = fmaf(ww, hi16(v.z), a1.y);
            a1.z = fmaf(ww, lo16(v.w), a1.z);
            a1.w = fmaf(ww, hi16(v.w), a1.w);
        }
    }
}

// ---- fused dinv + z0 (8 lanes per node) -------------------------------------
__global__ void dinv_init_kernel(const int2* __restrict__ packed,
                                 const int* __restrict__ offs,
                                 const float* __restrict__ user_w,
                                 const float* __restrict__ audio,
                                 const float* __restrict__ artist_w,
                                 const float* __restrict__ album_w,
                                 const int* __restrict__ artist_ids,
                                 const int* __restrict__ album_ids,
                                 float* __restrict__ dinv,
                                 ushort_t* __restrict__ z0) {
    unsigned t = blockIdx.x * 256u + threadIdx.x;
    unsigned node = t >> 3, c = t & 7u;
    if (node >= NN) return;
    int beg = offs[node], end = offs[node + 1];
    float ds = 0.f;
    for (int k = beg + (int)c; k < end; k += 8) ds += __int_as_float(packed[k].y);
    ds += __shfl_xor(ds, 1, 8);
    ds += __shfl_xor(ds, 2, 8);
    ds += __shfl_xor(ds, 4, 8);
    float d = (ds > 0.f) ? rsqrtf(ds) : 0.f;
    if (c == 0) dinv[node] = d;

    size_t ri = (size_t)node * 64u + c * 8u;
    float v[8];
    if (node < NUM_USERS) {
        float4 x0 = *(const float4*)(user_w + ri);
        float4 x1 = *(const float4*)(user_w + ri + 4);
        v[0]=x0.x; v[1]=x0.y; v[2]=x0.z; v[3]=x0.w;
        v[4]=x1.x; v[5]=x1.y; v[6]=x1.z; v[7]=x1.w;
    } else {
        unsigned j = node - NUM_USERS;
        unsigned aid = (unsigned)artist_ids[j], bid = (unsigned)album_ids[j];
        const float* ap = artist_w + (size_t)aid * 64u + c * 8u;
        const float* bp = album_w  + (size_t)bid * 64u + c * 8u;
        const float* up = audio    + (size_t)j   * 64u + c * 8u;
        float4 A0 = *(const float4*)ap, A1 = *(const float4*)(ap + 4);
        float4 B0 = *(const float4*)bp, B1 = *(const float4*)(bp + 4);
        float4 U0 = *(const float4*)up, U1 = *(const float4*)(up + 4);
        v[0] = fmaf(0.44f, A0.x + B0.x, 0.3f * U0.x);
        v[1] = fmaf(0.44f, A0.y + B0.y, 0.3f * U0.y);
        v[2] = fmaf(0.44f, A0.z + B0.z, 0.3f * U0.z);
        v[3] = fmaf(0.44f, A0.w + B0.w, 0.3f * U0.w);
        v[4] = fmaf(0.44f, A1.x + B1.x, 0.3f * U1.x);
        v[5] = fmaf(0.44f, A1.y + B1.y, 0.3f * U1.y);
        v[6] = fmaf(0.44f, A1.z + B1.z, 0.3f * U1.z);
        v[7] = fmaf(0.44f, A1.w + B1.w, 0.3f * U1.w);
    }
    float s = 0.f;
#pragma unroll
    for (int k = 0; k < 8; ++k) s = fmaf(v[k], v[k], s);
    s += __shfl_xor(s, 1, 8);
    s += __shfl_xor(s, 2, 8);
    s += __shfl_xor(s, 4, 8);
    float rn = rsqrtf(fmaxf(s, 1e-24f));          // == 1/max(||x||,1e-12)
    float scale = ((d > 0.f) ? d : 1.f) * rn;
    uint4 o;
    o.x = pack2(v[0] * scale, v[1] * scale);
    o.y = pack2(v[2] * scale, v[3] * scale);
    o.z = pack2(v[4] * scale, v[5] * scale);
    o.w = pack2(v[6] * scale, v[7] * scale);
    *(uint4*)(z0 + ri) = o;
}

// ---- SpMM layer in z-space: zout[n] = dinv_n^2 * sum ew * zin[row] ----------
__global__ void spmm_kernel(const ushort_t* __restrict__ zin,
                            const int2* __restrict__ packed,
                            const int* __restrict__ offs,
                            const float* __restrict__ dinv,
                            ushort_t* __restrict__ zout) {
    unsigned t = blockIdx.x * 256u + threadIdx.x;
    unsigned node = t >> 3, c = t & 7u;
    if (node >= NN) return;
    float d = dinv[node];                         // early scalar load
    float4 a0 = make_float4(0,0,0,0), a1 = make_float4(0,0,0,0);
    gather_node8(zin, packed, offs[node], offs[node + 1], c, a0, a1);
    float dd = d * d;
    uint4 o;
    o.x = pack2(a0.x * dd, a0.y * dd);
    o.y = pack2(a0.z * dd, a0.w * dd);
    o.z = pack2(a1.x * dd, a1.y * dd);
    o.w = pack2(a1.z * dd, a1.w * dd);
    *(uint4*)(zout + (size_t)node * 64u + c * 8u) = o;
}

// ---- final layer fused with l2norm: out = l2norm((z0+z1+z2+z3)/4) -----------
__global__ void spmm_final_kernel(const ushort_t* __restrict__ z0,
                                  const ushort_t* __restrict__ z1,
                                  const ushort_t* __restrict__ z2,
                                  const int2* __restrict__ packed,
                                  const int* __restrict__ offs,
                                  const float* __restrict__ dinv,
                                  float* __restrict__ out) {
    unsigned t = blockIdx.x * 256u + threadIdx.x;
    unsigned node = t >> 3, c = t & 7u;
    if (node >= NN) return;
    float d = dinv[node];
    float4 a0 = make_float4(0,0,0,0), a1 = make_float4(0,0,0,0);
    gather_node8(z2, packed, offs[node], offs[node + 1], c, a0, a1);
    float dd = d * d;
    size_t ri = (size_t)node * 64u + c * 8u;
    uint4 p0 = *(const uint4*)(z0 + ri);
    uint4 p1 = *(const uint4*)(z1 + ri);
    uint4 p2 = *(const uint4*)(z2 + ri);
    float v[8];
    v[0] = lo16(p0.x) + lo16(p1.x) + lo16(p2.x) + a0.x * dd;
    v[1] = hi16(p0.x) + hi16(p1.x) + hi16(p2.x) + a0.y * dd;
    v[2] = lo16(p0.y) + lo16(p1.y) + lo16(p2.y) + a0.z * dd;
    v[3] = hi16(p0.y) + hi16(p1.y) + hi16(p2.y) + a0.w * dd;
    v[4] = lo16(p0.z) + lo16(p1.z) + lo16(p2.z) + a1.x * dd;
    v[5] = hi16(p0.z) + hi16(p1.z) + hi16(p2.z) + a1.y * dd;
    v[6] = lo16(p0.w) + lo16(p1.w) + lo16(p2.w) + a1.z * dd;
    v[7] = hi16(p0.w) + hi16(p1.w) + hi16(p2.w) + a1.w * dd;
    float s = 0.f;
#pragma unroll
    for (int k = 0; k < 8; ++k) s = fmaf(v[k], v[k], s);
    s += __shfl_xor(s, 1, 8);
    s += __shfl_xor(s, 2, 8);
    s += __shfl_xor(s, 4, 8);
    float n = fmaxf(sqrtf(s) * 0.25f, 1e-12f);    // norm of acc/4, ref eps
    float inv = 0.25f / n;
    float4 o0 = make_float4(v[0]*inv, v[1]*inv, v[2]*inv, v[3]*inv);
    float4 o1 = make_float4(v[4]*inv, v[5]*inv, v[6]*inv, v[7]*inv);
    *(float4*)(out + ri)     = o0;
    *(float4*)(out + ri + 4) = o1;
    if (t == 0) out[(size_t)NN * 64u] = 0.f;      // align_loss
}

extern "C" void kernel_launch(void* const* d_in, const int* in_sizes, int n_in,
                              void* d_out, int out_size, void* d_ws, size_t ws_size,
                              hipStream_t stream) {
    const float* user_w     = (const float*)d_in[0];
    const float* audio      = (const float*)d_in[1];
    const float* artist_w   = (const float*)d_in[2];
    const float* album_w    = (const float*)d_in[3];
    const float* w1         = (const float*)d_in[4];
    const float* b1         = (const float*)d_in[5];
    const float* w2         = (const float*)d_in[6];
    const float* b2         = (const float*)d_in[7];
    const float* feats      = (const float*)d_in[8];
    const int*   row        = (const int*)d_in[9];
    const int*   col        = row + EE;
    const int*   artist_ids = (const int*)d_in[10];
    const int*   album_ids  = (const int*)d_in[11];
    float* out = (float*)d_out;

    // workspace (4B units): counts[NNP] offs[NNP+16] partials[1024]
    //                        er[EE int2] dinv[NN] packed[EE int2] z0..z2 ~79MB
    int*      counts   = (int*)d_ws;
    int*      offs     = counts + NNP;
    int*      partials = offs + NNP + 16;
    int2*     er       = (int2*)(partials + 1024);
    float*    dinv     = (float*)(er + EE);
    int2*     packed   = (int2*)(dinv + NN);
    ushort_t* z0       = (ushort_t*)(packed + EE);
    ushort_t* z1       = z0 + (size_t)NN * 64;
    ushort_t* z2       = z1 + (size_t)NN * 64;

    hipMemsetAsync(counts, 0, NNP * sizeof(int), stream);

    mlp_count_kernel<<<(EE + 255) / 256, 256, 0, stream>>>(feats, w1, b1, w2, b2,
                                                           col, er, counts);
    {
        void* args[] = { (void*)&counts, (void*)&offs, (void*)&partials,
                         (void*)&er, (void*)&row, (void*)&col, (void*)&packed };
        hipLaunchCooperativeKernel((const void*)scan_fill_kernel,
                                   dim3(NB), dim3(256), args, 0, stream);
    }
    dinv_init_kernel<<<G8_BLOCKS, 256, 0, stream>>>(packed, offs,
                                                    user_w, audio, artist_w, album_w,
                                                    artist_ids, album_ids, dinv, z0);
    spmm_kernel<<<G8_BLOCKS, 256, 0, stream>>>(z0, packed, offs, dinv, z1);
    spmm_kernel<<<G8_BLOCKS, 256, 0, stream>>>(z1, packed, offs, dinv, z2);
    spmm_final_kernel<<<G8_BLOCKS, 256, 0, stream>>>(z0, z1, z2, packed, offs,
                                                     dinv, out);
}